// Round 6
// baseline (1252.182 us; speedup 1.0000x reference)
//
#include <hip/hip_runtime.h>
#include <math.h>

// AdaAttN — all GEMMs on bf16 MFMA. Round 6: AV back to 128^2 tile (16 MFMA
// per barrier, m97 shape) AND 3 blocks/CU via split-K=2 with fp32 atomicAdd
// (2 writers/elem -> order-invariant, deterministic). Rest unchanged.

constexpr int B = 4;
constexpr int C = 512;     // Cqk == Cv == 512
constexpr int N = 4096;    // H*W
constexpr int NC = 2048;   // n-chunk for logits/softmax
constexpr int C2 = 2 * C;  // split row length
constexpr int KS = 3 * C;  // split-GEMM depth (convs & logits)
constexpr int HK = N / 2;  // AV split-K half depth
constexpr float EPSN = 1e-12f;
constexpr float EPSV = 1e-8f;

typedef __attribute__((ext_vector_type(4))) float f32x4;
typedef __attribute__((ext_vector_type(8))) short bf16x8;

static __device__ __forceinline__ unsigned short f2bf(float x) {
    union { float f; unsigned u; } c; c.f = x;
    unsigned r = c.u + 0x7FFFu + ((c.u >> 16) & 1u);   // RNE (finite inputs)
    return (unsigned short)(r >> 16);
}
static __device__ __forceinline__ float bf2f(unsigned short b) {
    union { unsigned u; float f; } c; c.u = ((unsigned)b) << 16;
    return c.f;
}

// XCD-aware swizzle for 2D grids with gridDim.x==64: nwg %8==0 -> bijective.
static __device__ __forceinline__ void xcd_swz(int gy, int& bx, int& by) {
    int nwg = gy << 6;
    int oldid = blockIdx.y * 64 + blockIdx.x;
    int nid = (oldid & 7) * (nwg >> 3) + (oldid >> 3);
    bx = nid & 63;
    by = nid >> 6;
}

// ---------------------------------------------------------------------------
__global__ __launch_bounds__(256) void stats_kernel(
    const float* __restrict__ fcp, const float* __restrict__ fsp,
    const float* __restrict__ fc, float* __restrict__ stats)
{
    int c = blockIdx.x;
    int which = blockIdx.y;
    const float* src = (which == 0) ? fcp : ((which == 1) ? fsp : fc);
    float s = 0.f, s2 = 0.f;
    for (int b = 0; b < B; ++b) {
        const float4* p = reinterpret_cast<const float4*>(src + (size_t)(b * C + c) * N);
        for (int i = threadIdx.x; i < N / 4; i += 256) {
            float4 v = p[i];
            s  += v.x + v.y + v.z + v.w;
            s2 += v.x * v.x + v.y * v.y + v.z * v.z + v.w * v.w;
        }
    }
#pragma unroll
    for (int off = 32; off > 0; off >>= 1) {
        s  += __shfl_down(s, off);
        s2 += __shfl_down(s2, off);
    }
    __shared__ float w1[4], w2[4];
    if ((threadIdx.x & 63) == 0) { w1[threadIdx.x >> 6] = s; w2[threadIdx.x >> 6] = s2; }
    __syncthreads();
    if (threadIdx.x == 0) {
        float S  = w1[0] + w1[1] + w1[2] + w1[3];
        float S2 = w2[0] + w2[1] + w2[2] + w2[3];
        float n = (float)(B * N);
        float mean = S / n;
        float var = (S2 - S * S / n) / (n - 1.0f);
        var = fmaxf(var, 0.f);
        float inv = 1.0f / (sqrtf(var) + EPSN);
        stats[(which * C + c) * 2 + 0] = mean;
        stats[(which * C + c) * 2 + 1] = inv;
    }
}

// ---------------------------------------------------------------------------
__global__ __launch_bounds__(256) void eff_weights_split(
    const float* __restrict__ Wf, const float* __restrict__ bf_,
    const float* __restrict__ Wg, const float* __restrict__ bg_,
    const float* __restrict__ Wh, const float* __restrict__ bh_,
    const float* __restrict__ stats,
    unsigned short* __restrict__ Wsf, unsigned short* __restrict__ Wsg,
    unsigned short* __restrict__ Wsh,
    float* __restrict__ bpf, float* __restrict__ bpg, float* __restrict__ bph)
{
    int o = blockIdx.x;
    int which = blockIdx.y;
    const float* W    = (which == 0) ? Wf  : (which == 1) ? Wg  : Wh;
    const float* bias = (which == 0) ? bf_ : (which == 1) ? bg_ : bh_;
    unsigned short* Ws = (which == 0) ? Wsf : (which == 1) ? Wsg : Wsh;
    float* bp          = (which == 0) ? bpf : (which == 1) ? bpg : bph;
    float corr = 0.f;
    for (int c = threadIdx.x; c < C; c += 256) {
        float wp;
        if (which < 2) {
            const float* st = stats + which * C * 2;
            wp = W[o * C + c] * st[c * 2 + 1];
            corr += wp * st[c * 2 + 0];
        } else {
            wp = W[o * C + c];
        }
        unsigned short h = f2bf(wp);
        unsigned short l = f2bf(wp - bf2f(h));
        Ws[(size_t)o * C2 + c]     = h;
        Ws[(size_t)o * C2 + C + c] = l;
    }
#pragma unroll
    for (int off = 32; off > 0; off >>= 1) corr += __shfl_down(corr, off);
    __shared__ float wr[4];
    if ((threadIdx.x & 63) == 0) wr[threadIdx.x >> 6] = corr;
    __syncthreads();
    if (threadIdx.x == 0) bp[o] = bias[o] - (wr[0] + wr[1] + wr[2] + wr[3]);
}

// ---------------------------------------------------------------------------
// Transpose + exact bf16 split: F [C][N] f32 -> Xs [N][2C] bf16 (h | l). z = which input.
__global__ __launch_bounds__(256) void in_split_all(
    const float* __restrict__ F0, const float* __restrict__ F1,
    const float* __restrict__ F2,
    unsigned short* __restrict__ X0, unsigned short* __restrict__ X1,
    unsigned short* __restrict__ X2)
{
    int z = blockIdx.z;
    const float* F = (z == 0) ? F0 : (z == 1) ? F1 : F2;
    unsigned short* Xs = (z == 0) ? X0 : (z == 1) ? X1 : X2;
    __shared__ float t[64][65];
    int n0 = blockIdx.x * 64, c0 = blockIdx.y * 64;
    int tx = threadIdx.x & 15, ty = threadIdx.x >> 4;
#pragma unroll
    for (int it = 0; it < 4; ++it) {
        int cl = ty + it * 16;
        float4 v = *reinterpret_cast<const float4*>(&F[(size_t)(c0 + cl) * N + n0 + tx * 4]);
        t[cl][tx * 4 + 0] = v.x; t[cl][tx * 4 + 1] = v.y;
        t[cl][tx * 4 + 2] = v.z; t[cl][tx * 4 + 3] = v.w;
    }
    __syncthreads();
#pragma unroll
    for (int it = 0; it < 4; ++it) {
        int nl = ty + it * 16;
        unsigned short h[4], l[4];
#pragma unroll
        for (int j = 0; j < 4; ++j) {
            float v = t[tx * 4 + j][nl];
            h[j] = f2bf(v);
            l[j] = f2bf(v - bf2f(h[j]));
        }
        size_t base = (size_t)(n0 + nl) * C2 + c0 + tx * 4;
        *reinterpret_cast<ushort4*>(&Xs[base])     = make_ushort4(h[0], h[1], h[2], h[3]);
        *reinterpret_cast<ushort4*>(&Xs[base + C]) = make_ushort4(l[0], l[1], l[2], l[3]);
    }
}

// ---------------------------------------------------------------------------
// 3-way conv, tile 128(o) x 64(n), K=1536 stacked. z=0:Q z=1:K (transposed split
// out), z=2: V -> T rows [bf16(V); qh; ql].
__global__ __launch_bounds__(256) void conv_all(
    const unsigned short* __restrict__ Wsf, const unsigned short* __restrict__ Wsg,
    const unsigned short* __restrict__ Wsh,
    const unsigned short* __restrict__ X0, const unsigned short* __restrict__ X1,
    const unsigned short* __restrict__ X2,
    const float* __restrict__ bpf, const float* __restrict__ bpg,
    const float* __restrict__ bph,
    unsigned short* __restrict__ Qs, unsigned short* __restrict__ Ks,
    unsigned short* __restrict__ Tb)
{
    int z = blockIdx.z;
    const unsigned short* Ws = (z == 0) ? Wsf : (z == 1) ? Wsg : Wsh;
    const unsigned short* Xs = (z == 0) ? X0  : (z == 1) ? X1  : X2;
    const float* bias        = (z == 0) ? bpf : (z == 1) ? bpg : bph;

    __shared__ unsigned short lA[128 * 32];
    __shared__ unsigned short lB[64 * 32];
    const int tid  = threadIdx.x;
    const int wave = tid >> 6, lane = tid & 63;
    int bx, by; xcd_swz(4, bx, by);
    const int o0 = by * 128;
    const int n0 = bx * 64;
    const int wr = (wave >> 1) * 64, wc = (wave & 1) * 32;
    f32x4 acc[4][2] = {};
    const int r1 = tid >> 2, c1 = (tid & 3) * 8;
    const int r2 = r1 + 64;
    const int rowA = lane & 15;
    const int kk   = (lane >> 4) * 8;

    for (int k0 = 0; k0 < KS; k0 += 32) {
        int acol = (k0 < 1024) ? k0 : k0 - 1024;
        int bcol = (k0 < 512)  ? k0 : k0 - 512;
        __syncthreads();
        __builtin_amdgcn_global_load_lds(
            (const __attribute__((address_space(1))) void*)&Ws[(size_t)(o0 + r1) * C2 + acol + c1],
            (__attribute__((address_space(3))) void*)&lA[wave * 512], 16, 0, 0);
        __builtin_amdgcn_global_load_lds(
            (const __attribute__((address_space(1))) void*)&Ws[(size_t)(o0 + r2) * C2 + acol + c1],
            (__attribute__((address_space(3))) void*)&lA[2048 + wave * 512], 16, 0, 0);
        __builtin_amdgcn_global_load_lds(
            (const __attribute__((address_space(1))) void*)&Xs[(size_t)(n0 + r1) * C2 + bcol + c1],
            (__attribute__((address_space(3))) void*)&lB[wave * 512], 16, 0, 0);
        asm volatile("s_waitcnt vmcnt(0)" ::: "memory");
        __syncthreads();

        bf16x8 af[4], bfv[2];
#pragma unroll
        for (int f = 0; f < 4; ++f)
            af[f]  = *reinterpret_cast<const bf16x8*>(&lA[(wr + f * 16 + rowA) * 32 + kk]);
#pragma unroll
        for (int f = 0; f < 2; ++f)
            bfv[f] = *reinterpret_cast<const bf16x8*>(&lB[(wc + f * 16 + rowA) * 32 + kk]);
#pragma unroll
        for (int fm = 0; fm < 4; ++fm)
#pragma unroll
            for (int fn = 0; fn < 2; ++fn)
                acc[fm][fn] = __builtin_amdgcn_mfma_f32_16x16x32_bf16(
                    af[fm], bfv[fn], acc[fm][fn], 0, 0, 0);
    }

    const int colD = lane & 15, rowD = (lane >> 4) * 4;
#pragma unroll
    for (int fm = 0; fm < 4; ++fm) {
        int ob = o0 + wr + fm * 16 + rowD;
        float4 b4 = *reinterpret_cast<const float4*>(&bias[ob]);
        float bv[4] = {b4.x, b4.y, b4.z, b4.w};
#pragma unroll
        for (int fn = 0; fn < 2; ++fn) {
            int n = n0 + wc + fn * 16 + colD;
            if (z < 2) {
                unsigned short* Yt = (z == 0) ? Qs : Ks;
                unsigned short hh[4], ll[4];
#pragma unroll
                for (int r = 0; r < 4; ++r) {
                    float val = acc[fm][fn][r] + bv[r];
                    hh[r] = f2bf(val);
                    ll[r] = f2bf(val - bf2f(hh[r]));
                }
                size_t base = (size_t)n * C2 + ob;
                *reinterpret_cast<ushort4*>(&Yt[base])     = make_ushort4(hh[0], hh[1], hh[2], hh[3]);
                *reinterpret_cast<ushort4*>(&Yt[base + C]) = make_ushort4(ll[0], ll[1], ll[2], ll[3]);
            } else {
#pragma unroll
                for (int r = 0; r < 4; ++r) {
                    float val = acc[fm][fn][r] + bv[r];
                    unsigned short vb = f2bf(val);
                    float vh = bf2f(vb);
                    float sq = vh * vh;                 // exact in fp32
                    unsigned short qb = f2bf(sq);
                    unsigned short lb = f2bf(sq - bf2f(qb));
                    size_t rowb = (size_t)(ob + r) * N + n;
                    Tb[rowb]                     = vb;
                    Tb[rowb + (size_t)C * N]     = qb;
                    Tb[rowb + (size_t)2 * C * N] = lb;
                }
            }
        }
    }
}

// ---------------------------------------------------------------------------
// Logits: L[nl,m] = sum_{k<1536} Qstack[nbase+nl,k]*Kstack[m,k]. Tile 128(n)x64(m).
__global__ __launch_bounds__(256) void gemm_qtk_mfma(
    const unsigned short* __restrict__ Qs,   // [N][2C]
    const unsigned short* __restrict__ Ks,   // [N][2C]
    float* __restrict__ L, int nbase)
{
    __shared__ unsigned short lA[128 * 32];
    __shared__ unsigned short lB[64 * 32];
    const int tid  = threadIdx.x;
    const int wave = tid >> 6, lane = tid & 63;
    int bx, by; xcd_swz(16, bx, by);
    const int nl0 = by * 128;
    const int qn0 = nbase + nl0;
    const int m0  = bx * 64;
    const int wr = (wave >> 1) * 64, wc = (wave & 1) * 32;
    f32x4 acc[4][2] = {};
    const int r1 = tid >> 2, c1 = (tid & 3) * 8;
    const int r2 = r1 + 64;
    const int rowA = lane & 15;
    const int kk   = (lane >> 4) * 8;

    for (int k0 = 0; k0 < KS; k0 += 32) {
        int acol = (k0 < 1024) ? k0 : k0 - 1024;   // [Qh;Ql;Qh]
        int bcol = (k0 < 512)  ? k0 : k0 - 512;    // [Kh;Kh;Kl]
        __syncthreads();
        __builtin_amdgcn_global_load_lds(
            (const __attribute__((address_space(1))) void*)&Qs[(size_t)(qn0 + r1) * C2 + acol + c1],
            (__attribute__((address_space(3))) void*)&lA[wave * 512], 16, 0, 0);
        __builtin_amdgcn_global_load_lds(
            (const __attribute__((address_space(1))) void*)&Qs[(size_t)(qn0 + r2) * C2 + acol + c1],
            (__attribute__((address_space(3))) void*)&lA[2048 + wave * 512], 16, 0, 0);
        __builtin_amdgcn_global_load_lds(
            (const __attribute__((address_space(1))) void*)&Ks[(size_t)(m0 + r1) * C2 + bcol + c1],
            (__attribute__((address_space(3))) void*)&lB[wave * 512], 16, 0, 0);
        asm volatile("s_waitcnt vmcnt(0)" ::: "memory");
        __syncthreads();

        bf16x8 af[4], bfv[2];
#pragma unroll
        for (int f = 0; f < 4; ++f)
            af[f]  = *reinterpret_cast<const bf16x8*>(&lA[(wr + f * 16 + rowA) * 32 + kk]);
#pragma unroll
        for (int f = 0; f < 2; ++f)
            bfv[f] = *reinterpret_cast<const bf16x8*>(&lB[(wc + f * 16 + rowA) * 32 + kk]);
#pragma unroll
        for (int fm = 0; fm < 4; ++fm)
#pragma unroll
            for (int fn = 0; fn < 2; ++fn)
                acc[fm][fn] = __builtin_amdgcn_mfma_f32_16x16x32_bf16(
                    af[fm], bfv[fn], acc[fm][fn], 0, 0, 0);
    }

    const int colD = lane & 15, rowD = (lane >> 4) * 4;
#pragma unroll
    for (int fm = 0; fm < 4; ++fm)
#pragma unroll
        for (int fn = 0; fn < 2; ++fn) {
            int col = m0 + wc + fn * 16 + colD;
            int row = nl0 + wr + fm * 16 + rowD;
#pragma unroll
            for (int r = 0; r < 4; ++r)
                L[(size_t)(row + r) * N + col] = acc[fm][fn][r];
        }
}

// ---------------------------------------------------------------------------
// Row softmax -> unnormalized bf16 weights (into chunk's E region) + fp32 1/rowsum.
__global__ __launch_bounds__(256) void softmax_bf16(
    const float* __restrict__ L, unsigned short* __restrict__ E,
    float* __restrict__ rinv, int nbase)
{
    __shared__ float row[N];
    __shared__ float red[4];
    const float* Lr = L + (size_t)blockIdx.x * N;
    unsigned short* Er = E + (size_t)blockIdx.x * N;
    float mx = -3.0e38f;
    for (int i = threadIdx.x; i < N / 4; i += 256) {
        float4 v = reinterpret_cast<const float4*>(Lr)[i];
        reinterpret_cast<float4*>(row)[i] = v;
        mx = fmaxf(fmaxf(mx, fmaxf(v.x, v.y)), fmaxf(v.z, v.w));
    }
#pragma unroll
    for (int off = 32; off > 0; off >>= 1) mx = fmaxf(mx, __shfl_xor(mx, off));
    if ((threadIdx.x & 63) == 0) red[threadIdx.x >> 6] = mx;
    __syncthreads();
    mx = fmaxf(fmaxf(red[0], red[1]), fmaxf(red[2], red[3]));
    __syncthreads();
    float s = 0.f;
    for (int i = threadIdx.x; i < N / 4; i += 256) {
        float4 v = reinterpret_cast<float4*>(row)[i];
        unsigned short e0 = f2bf(__expf(v.x - mx));
        unsigned short e1 = f2bf(__expf(v.y - mx));
        unsigned short e2 = f2bf(__expf(v.z - mx));
        unsigned short e3 = f2bf(__expf(v.w - mx));
        s += bf2f(e0) + bf2f(e1) + bf2f(e2) + bf2f(e3);
        reinterpret_cast<ushort4*>(Er)[i] = make_ushort4(e0, e1, e2, e3);
    }
#pragma unroll
    for (int off = 32; off > 0; off >>= 1) s += __shfl_xor(s, off);
    if ((threadIdx.x & 63) == 0) red[threadIdx.x >> 6] = s;
    __syncthreads();
    if (threadIdx.x == 0)
        rinv[nbase + blockIdx.x] = 1.0f / (red[0] + red[1] + red[2] + red[3]);
}

// ---------------------------------------------------------------------------
// Moments, split-K=2: each block accumulates its half of m into P via fp32
// atomicAdd (exactly 2 writers/elem -> order-invariant, deterministic).
// Tile 128(v) x 128(n), BK=32 (m97 shape). P must be pre-zeroed.
__global__ __launch_bounds__(256) void gemm_av_splitk(
    const unsigned short* __restrict__ T,    // [3C][N]
    const unsigned short* __restrict__ E0,   // rows [0,2048)
    const unsigned short* __restrict__ E1,   // rows [2048,4096)
    float* __restrict__ P)                   // [3C][N] (zero-initialized)
{
    __shared__ unsigned short lA[128 * 32];
    __shared__ unsigned short lB[128 * 32];
    const int tid  = threadIdx.x;
    const int wave = tid >> 6, lane = tid & 63;
    // 3D swizzle: 768 blocks -> 8 chunks of 96; consecutive lid share an E-panel.
    int hid = blockIdx.x + 32 * (blockIdx.y + 12 * blockIdx.z);
    int lid = (hid & 7) * 96 + (hid >> 3);
    int by  = lid % 12;          // v-tile
    int rest = lid / 12;
    int bx  = rest & 31;         // n-tile
    int kz  = rest >> 5;         // k-half
    const int v0 = by * 128;
    const int n0 = bx * 128;
    const int kbeg = kz * HK;
    const unsigned short* Ep = (n0 < NC) ? E0 + (size_t)n0 * N
                                         : E1 + (size_t)(n0 - NC) * N;
    const int wr = (wave >> 1) * 64, wc = (wave & 1) * 64;
    f32x4 acc[4][4] = {};
    const int r1 = tid >> 2, c1 = (tid & 3) * 8;
    const int r2 = r1 + 64;
    const int rowA = lane & 15;
    const int kk   = (lane >> 4) * 8;

    for (int k0 = kbeg; k0 < kbeg + HK; k0 += 32) {
        __syncthreads();
        __builtin_amdgcn_global_load_lds(
            (const __attribute__((address_space(1))) void*)&T[(size_t)(v0 + r1) * N + k0 + c1],
            (__attribute__((address_space(3))) void*)&lA[wave * 512], 16, 0, 0);
        __builtin_amdgcn_global_load_lds(
            (const __attribute__((address_space(1))) void*)&T[(size_t)(v0 + r2) * N + k0 + c1],
            (__attribute__((address_space(3))) void*)&lA[2048 + wave * 512], 16, 0, 0);
        __builtin_amdgcn_global_load_lds(
            (const __attribute__((address_space(1))) void*)&Ep[(size_t)r1 * N + k0 + c1],
            (__attribute__((address_space(3))) void*)&lB[wave * 512], 16, 0, 0);
        __builtin_amdgcn_global_load_lds(
            (const __attribute__((address_space(1))) void*)&Ep[(size_t)r2 * N + k0 + c1],
            (__attribute__((address_space(3))) void*)&lB[2048 + wave * 512], 16, 0, 0);
        asm volatile("s_waitcnt vmcnt(0)" ::: "memory");
        __syncthreads();

        bf16x8 af[4], bfv[4];
#pragma unroll
        for (int f = 0; f < 4; ++f) {
            af[f]  = *reinterpret_cast<const bf16x8*>(&lA[(wr + f * 16 + rowA) * 32 + kk]);
            bfv[f] = *reinterpret_cast<const bf16x8*>(&lB[(wc + f * 16 + rowA) * 32 + kk]);
        }
#pragma unroll
        for (int fm = 0; fm < 4; ++fm)
#pragma unroll
            for (int fn = 0; fn < 4; ++fn)
                acc[fm][fn] = __builtin_amdgcn_mfma_f32_16x16x32_bf16(
                    af[fm], bfv[fn], acc[fm][fn], 0, 0, 0);
    }

    const int colD = lane & 15, rowD = (lane >> 4) * 4;
#pragma unroll
    for (int fm = 0; fm < 4; ++fm)
#pragma unroll
        for (int fn = 0; fn < 4; ++fn) {
            int col = n0 + wc + fn * 16 + colD;
            int row = v0 + wr + fm * 16 + rowD;
#pragma unroll
            for (int r = 0; r < 4; ++r)
                unsafeAtomicAdd(&P[(size_t)(row + r) * N + col], acc[fm][fn][r]);
        }
}

// ---------------------------------------------------------------------------
// Full-N moment epilogue.
__global__ __launch_bounds__(256) void av_epilogue(
    const float* __restrict__ P, const float* __restrict__ rinv,
    const float* __restrict__ Fc, const float* __restrict__ st3,
    float* __restrict__ out)
{
    int idx = blockIdx.x * 256 + threadIdx.x;      // over C*N/4
    int v = idx >> 10;                             // / (N/4)
    int n = (idx & 1023) * 4;
    float4 pm = *reinterpret_cast<const float4*>(&P[(size_t)v * N + n]);
    float4 ph = *reinterpret_cast<const float4*>(&P[(size_t)(C + v) * N + n]);
    float4 pl = *reinterpret_cast<const float4*>(&P[(size_t)(2 * C + v) * N + n]);
    float4 ri = *reinterpret_cast<const float4*>(&rinv[n]);
    float mean = st3[v * 2], inv = st3[v * 2 + 1];
    float4 fc = *reinterpret_cast<const float4*>(&Fc[(size_t)v * N + n]);
    float pmv[4] = {pm.x, pm.y, pm.z, pm.w};
    float phv[4] = {ph.x + pl.x, ph.y + pl.y, ph.z + pl.z, ph.w + pl.w};
    float riv[4] = {ri.x, ri.y, ri.z, ri.w};
    float fcv[4] = {fc.x, fc.y, fc.z, fc.w};
    float o[4];
#pragma unroll
    for (int q = 0; q < 4; ++q) {
        float M  = pmv[q] * riv[q];
        float S2 = phv[q] * riv[q];
        float var = fmaxf(S2 - M * M, 0.f) + EPSV;
        o[q] = sqrtf(var) * ((fcv[q] - mean) * inv) + M;
    }
    *reinterpret_cast<float4*>(&out[(size_t)v * N + n]) =
        make_float4(o[0], o[1], o[2], o[3]);
}

// ---------------------------------------------------------------------------
extern "C" void kernel_launch(void* const* d_in, const int* in_sizes, int n_in,
                              void* d_out, int out_size, void* d_ws, size_t ws_size,
                              hipStream_t stream)
{
    const float* F_c      = (const float*)d_in[0];
    const float* F_s      = (const float*)d_in[1];
    const float* F_c_prev = (const float*)d_in[2];
    const float* F_s_prev = (const float*)d_in[3];
    const float* Wf = (const float*)d_in[4];
    const float* bf_ = (const float*)d_in[5];
    const float* Wg = (const float*)d_in[6];
    const float* bg_ = (const float*)d_in[7];
    const float* Wh = (const float*)d_in[8];
    const float* bh_ = (const float*)d_in[9];
    float* out = (float*)d_out;

    // byte-offset workspace carve-up, 256B aligned regions
    char* base = (char*)d_ws;
    size_t off = 0;
    auto alloc = [&](size_t bytes) { void* p = base + off; off = (off + bytes + 255) & ~(size_t)255; return p; };
    float* stats = (float*)alloc(3 * C * 2 * 4);
    float* bpf   = (float*)alloc(C * 4);
    float* bpg   = (float*)alloc(C * 4);
    float* bph   = (float*)alloc(C * 4);
    float* rinv  = (float*)alloc(N * 4);
    unsigned short* Wsf = (unsigned short*)alloc((size_t)C * C2 * 2);   // 1 MB each
    unsigned short* Wsg = (unsigned short*)alloc((size_t)C * C2 * 2);
    unsigned short* Wsh = (unsigned short*)alloc((size_t)C * C2 * 2);
    // Region A (16.78 MB): Qs|Ks during conv+qtk; E rows [2048,4096) afterwards.
    char* Areg = (char*)alloc((size_t)2 * N * C2 * 2);
    unsigned short* Qs = (unsigned short*)Areg;
    unsigned short* Ks = (unsigned short*)(Areg + (size_t)N * C2 * 2);
    unsigned short* E1 = (unsigned short*)Areg;
    // Region B (33.55 MB): Xs0/1/2 during in_split+conv; L during qtk/softmax;
    // P (25.17 MB, zeroed) during AV+epilogue.
    char* Breg = (char*)alloc((size_t)NC * N * 4);
    unsigned short* Xs0 = (unsigned short*)Breg;
    unsigned short* Xs1 = (unsigned short*)(Breg + (size_t)N * C2 * 2);
    unsigned short* Xs2 = (unsigned short*)(Breg + (size_t)2 * N * C2 * 2);
    float* Lb = (float*)Breg;
    float* Pb = (float*)Breg;
    unsigned short* Tb = (unsigned short*)alloc((size_t)3 * C * N * 2); // 12.58 MB
    unsigned short* E0 = (unsigned short*)alloc((size_t)NC * N * 2);    // 16.78 MB
    if (ws_size < off) return;  // insufficient scratch -> visible failure

    hipLaunchKernelGGL(stats_kernel, dim3(C, 3), dim3(256), 0, stream,
                       F_c_prev, F_s_prev, F_c, stats);
    hipLaunchKernelGGL(eff_weights_split, dim3(C, 3), dim3(256), 0, stream,
                       Wf, bf_, Wg, bg_, Wh, bh_, stats, Wsf, Wsg, Wsh, bpf, bpg, bph);

    for (int b = 0; b < B; ++b) {
        const float* Xq = F_c_prev + (size_t)b * C * N;
        const float* Xk = F_s_prev + (size_t)b * C * N;
        const float* Xv = F_s      + (size_t)b * C * N;

        hipLaunchKernelGGL(in_split_all, dim3(N / 64, C / 64, 3), dim3(256), 0, stream,
                           Xq, Xk, Xv, Xs0, Xs1, Xs2);
        hipLaunchKernelGGL(conv_all, dim3(N / 64, C / 128, 3), dim3(256), 0, stream,
                           Wsf, Wsg, Wsh, Xs0, Xs1, Xs2, bpf, bpg, bph, Qs, Ks, Tb);

        // chunk 0: logits -> E0
        hipLaunchKernelGGL(gemm_qtk_mfma, dim3(N / 64, NC / 128), dim3(256), 0, stream,
                           Qs, Ks, Lb, 0);
        hipLaunchKernelGGL(softmax_bf16, dim3(NC), dim3(256), 0, stream, Lb, E0, rinv, 0);
        // chunk 1: logits -> E1 (overlays dead Qs/Ks after qtk reads them)
        hipLaunchKernelGGL(gemm_qtk_mfma, dim3(N / 64, NC / 128), dim3(256), 0, stream,
                           Qs, Ks, Lb, NC);
        hipLaunchKernelGGL(softmax_bf16, dim3(NC), dim3(256), 0, stream, Lb, E1, rinv, NC);
        // zero P (region B is dead: L consumed by both softmax passes)
        hipMemsetAsync(Pb, 0, (size_t)3 * C * N * 4, stream);
        // split-K AV over full N, atomic accumulate
        hipLaunchKernelGGL(gemm_av_splitk, dim3(N / 128, 3 * C / 128, 2), dim3(256), 0, stream,
                           Tb, E0, E1, Pb);
        hipLaunchKernelGGL(av_epilogue, dim3((C * N / 4) / 256), dim3(256), 0, stream,
                           Pb, rinv, F_c + (size_t)b * C * N, stats + 2 * C * 2,
                           out + (size_t)b * C * N);
    }
}